// Round 1
// baseline (3571.928 us; speedup 1.0000x reference)
//
#include <hip/hip_runtime.h>
#include <cstdint>
#include <cstddef>

// Problem constants
#define B_SZ 512
#define S_SZ 120
#define D_SZ 216
#define H_SZ 1024
#define NG   4096     // 4*H
#define DP   224      // D padded to multiple of 32
#define KENC 1248     // DP + H
#define TMAX 24

// GEMM tile config
#define BM 64
#define BN 128
#define BK 32

using bf16_t = __bf16;
using bf16x8 = __attribute__((ext_vector_type(8))) __bf16;
using f32x4  = __attribute__((ext_vector_type(4))) float;

__device__ __forceinline__ void gload16(const void* g, void* l) {
  __builtin_amdgcn_global_load_lds(
      (const __attribute__((address_space(1))) void*)g,
      (__attribute__((address_space(3))) void*)l, 16, 0, 0);
}

__device__ __forceinline__ float fsigmoid(float x) {
  x = fminf(fmaxf(x, -30.f), 30.f);
  return 1.f / (1.f + __expf(-x));
}
__device__ __forceinline__ float ftanh(float x) {
  x = fminf(fmaxf(x, -15.f), 15.f);
  float e = __expf(2.f * x);
  return (e - 1.f) / (e + 1.f);
}

struct __align__(16) Smem {
  union {
    struct { bf16_t A[BM * BK]; bf16_t B[BN * BK]; } st;  // 12288 B staging
    float gate[BM * 129];                                  // 33024 B epilogue restage
  };
};

// C[m][n] = sum_k A[m][k] * W[n][k]  (A,W row-major with K innermost; W is "B^T")
// A comes in up to two phases: (A1,sA1,n1 iters) then (A2,sA2,n2 iters); W's k
// column advances continuously across phases.
// EPI=1: LSTM cell epilogue (bias, cbuf fp32 in/out, hout bf16)
// EPI=2: out_bf16[m][n] = bf16(acc + addm[orig(m)][n])   (W_dec build)
// EPI=3: outf[(b*24+t)*216+n] = acc + bias[n], m = t*512+b, guard n<216
template <int EPI>
__global__ __launch_bounds__(256, 1) void gemm_step(
    const bf16_t* __restrict__ A1, int sA1, int n1,
    const bf16_t* __restrict__ A2, int sA2, int n2,
    const bf16_t* __restrict__ W, int sW,
    const float* __restrict__ bias,
    float* __restrict__ cbuf, bf16_t* __restrict__ hout,
    const float* __restrict__ addm, bf16_t* __restrict__ outb,
    float* __restrict__ outf)
{
  __shared__ Smem sm;
  const int t    = threadIdx.x;
  const int m0   = blockIdx.y * BM;
  const int n0   = blockIdx.x * BN;
  const int lane = t & 63;
  const int wv   = t >> 6;
  const int wm   = wv >> 1, wn = wv & 1;   // 2x2 wave grid, wave tile 32x64
  const int fr   = lane & 15;
  const int fq   = lane >> 4;

  f32x4 acc[2][4] = {};

  // Loader indices: slot s covers row s>>2, 16B chunk (s&3)
  const int ar = t >> 2;
  const int ac = (t & 3) * 8;  // element offset within row

  // Wave-uniform LDS destinations (HW writes base + lane*16)
  char* ldsA  = (char*)sm.st.A + (t >> 6) * 1024;
  char* ldsB0 = (char*)sm.st.B + (t >> 6) * 1024;
  char* ldsB1 = (char*)sm.st.B + 4096 + (t >> 6) * 1024;

  // Fragment LDS element offsets (row-major [rows][BK])
  const int aOff = (wm * 32 + fr) * BK + fq * 8;
  const int bOff = (wn * 64 + fr) * BK + fq * 8;

  const bf16_t* APs[2] = {A1, A2};
  int sAs[2] = {sA1, sA2};
  int nIt[2] = {n1, n2};
  int kb = 0;
  for (int ph = 0; ph < 2; ++ph) {
    int ni = nIt[ph];
    if (ni == 0) continue;
    const bf16_t* Ap = APs[ph];
    int sA = sAs[ph];
    const bf16_t* ga  = Ap + (size_t)(m0 + ar) * sA + ac;
    const bf16_t* gb0 = W + (size_t)(n0 + ar) * sW + kb + ac;
    const bf16_t* gb1 = W + (size_t)(n0 + 64 + ar) * sW + kb + ac;
    for (int it = 0; it < ni; ++it) {
      gload16(ga, ldsA);
      gload16(gb0, ldsB0);
      gload16(gb1, ldsB1);
      ga += BK; gb0 += BK; gb1 += BK;
      __syncthreads();  // drains vmcnt -> LDS tiles visible
      bf16x8 av0 = *(const bf16x8*)((const char*)sm.st.A + (size_t)aOff * 2);
      bf16x8 av1 = *(const bf16x8*)((const char*)sm.st.A + (size_t)(aOff + 16 * BK) * 2);
      bf16x8 bv[4];
#pragma unroll
      for (int j = 0; j < 4; ++j)
        bv[j] = *(const bf16x8*)((const char*)sm.st.B + (size_t)(bOff + j * 16 * BK) * 2);
#pragma unroll
      for (int j = 0; j < 4; ++j) {
        acc[0][j] = __builtin_amdgcn_mfma_f32_16x16x32_bf16(av0, bv[j], acc[0][j], 0, 0, 0);
        acc[1][j] = __builtin_amdgcn_mfma_f32_16x16x32_bf16(av1, bv[j], acc[1][j], 0, 0, 0);
      }
      __syncthreads();  // protect LDS before next staging
    }
    kb += ni * BK;
  }

  if (EPI == 1) {
    // Restage gates (fp32, +bias) to LDS, then apply LSTM cell.
    // N layout is gate-interleaved: n = 4*unit + gate (i,f,g,o)
#pragma unroll
    for (int i = 0; i < 2; ++i)
#pragma unroll
      for (int j = 0; j < 4; ++j)
#pragma unroll
        for (int v = 0; v < 4; ++v) {
          int row = wm * 32 + i * 16 + fq * 4 + v;
          int col = wn * 64 + j * 16 + fr;
          sm.gate[row * 129 + col] = acc[i][j][v] + bias[n0 + col];
        }
    __syncthreads();
    const int u0 = n0 >> 2;
#pragma unroll
    for (int itc = 0; itc < 8; ++itc) {
      int ci = itc * 256 + t;
      int brow = ci >> 5;   // 0..63 local batch row
      int ju   = ci & 31;   // 0..31 local unit
      const float* gp = &sm.gate[brow * 129 + ju * 4];
      float iv = fsigmoid(gp[0]);
      float fv = fsigmoid(gp[1]);
      float gv = ftanh(gp[2]);
      float ov = fsigmoid(gp[3]);
      size_t cix = (size_t)(m0 + brow) * H_SZ + (u0 + ju);
      float cn = fv * cbuf[cix] + iv * gv;
      cbuf[cix] = cn;
      hout[cix] = (bf16_t)(ov * ftanh(cn));
    }
  }

  if (EPI == 2) {
#pragma unroll
    for (int i = 0; i < 2; ++i)
#pragma unroll
      for (int j = 0; j < 4; ++j)
#pragma unroll
        for (int v = 0; v < 4; ++v) {
          int gr = m0 + wm * 32 + i * 16 + fq * 4 + v;
          int gc = n0 + wn * 64 + j * 16 + fr;
          int orig = (gr & 3) * H_SZ + (gr >> 2);
          float val = acc[i][j][v] + addm[(size_t)orig * H_SZ + gc];
          outb[(size_t)gr * H_SZ + gc] = (bf16_t)val;
        }
  }

  if (EPI == 3) {
#pragma unroll
    for (int i = 0; i < 2; ++i)
#pragma unroll
      for (int j = 0; j < 4; ++j)
#pragma unroll
        for (int v = 0; v < 4; ++v) {
          int m = m0 + wm * 32 + i * 16 + fq * 4 + v;
          int n = n0 + wn * 64 + j * 16 + fr;
          if (n < D_SZ) {
            int ts = m >> 9;     // /512
            int bb = m & 511;
            outf[((size_t)bb * TMAX + ts) * D_SZ + n] = acc[i][j][v] + bias[n];
          }
        }
  }
}

// src (B,S,D) fp32 -> srcbf (S,B,DP) bf16, zero-padded d>=216
__global__ void k_convert_src(const float* __restrict__ src, bf16_t* __restrict__ dst) {
  int idx = blockIdx.x * 256 + threadIdx.x;
  int total = S_SZ * B_SZ * DP;
  if (idx >= total) return;
  int d = idx % DP;
  int r = idx / DP;
  int b = r % B_SZ;
  int tt = r / B_SZ;
  float v = (d < D_SZ) ? src[((size_t)b * S_SZ + tt) * D_SZ + d] : 0.f;
  dst[idx] = (bf16_t)v;
}

// W_cat (NG x KENC) bf16, rows gate-interleaved: row r <- orig (r&3)*H + (r>>2)
// cols [0,216)=W_ih, [216,224)=0, [224,1248)=W_hh
__global__ void k_build_wcat(const float* __restrict__ Wih, const float* __restrict__ Whh,
                             bf16_t* __restrict__ Wcat) {
  int idx = blockIdx.x * 256 + threadIdx.x;
  if (idx >= NG * KENC) return;
  int k = idx % KENC;
  int r = idx / KENC;
  int o = (r & 3) * H_SZ + (r >> 2);
  float v;
  if (k < D_SZ)      v = Wih[(size_t)o * D_SZ + k];
  else if (k < DP)   v = 0.f;
  else               v = Whh[(size_t)o * H_SZ + (k - DP)];
  Wcat[idx] = (bf16_t)v;
}

// WoutB: (256 x H) bf16, row d (zero-pad d>=216), col h  -- B-operand for final proj
// WoutT: (H x DP) bf16, row h, col d (zero-pad)          -- B-operand for W_dec build
__global__ void k_build_wout(const float* __restrict__ Wout, bf16_t* __restrict__ WoutB,
                             bf16_t* __restrict__ WoutT) {
  int idx = blockIdx.x * 256 + threadIdx.x;
  if (idx < 256 * H_SZ) {
    int h = idx % H_SZ, d = idx / H_SZ;
    WoutB[idx] = (bf16_t)((d < D_SZ) ? Wout[(size_t)d * H_SZ + h] : 0.f);
  }
  if (idx < H_SZ * DP) {
    int d = idx % DP, h = idx / DP;
    WoutT[idx] = (bf16_t)((d < D_SZ) ? Wout[(size_t)d * H_SZ + h] : 0.f);
  }
}

// bias_enc[r] = b_ih[o]+b_hh[o];  bias_dec[r] = bias_enc[r] + W_ih[o,:] . b_out
__global__ void k_build_bias(const float* __restrict__ bih, const float* __restrict__ bhh,
                             const float* __restrict__ Wih, const float* __restrict__ bout,
                             float* __restrict__ biasE, float* __restrict__ biasD) {
  int r = blockIdx.x * 256 + threadIdx.x;
  if (r >= NG) return;
  int o = (r & 3) * H_SZ + (r >> 2);
  float be = bih[o] + bhh[o];
  biasE[r] = be;
  float s = 0.f;
  const float* wr = Wih + (size_t)o * D_SZ;
  for (int d = 0; d < D_SZ; ++d) s += wr[d] * bout[d];
  biasD[r] = be + s;
}

extern "C" void kernel_launch(void* const* d_in, const int* in_sizes, int n_in,
                              void* d_out, int out_size, void* d_ws, size_t ws_size,
                              hipStream_t stream) {
  const float* src  = (const float*)d_in[0];
  const float* Wih  = (const float*)d_in[1];
  const float* Whh  = (const float*)d_in[2];
  const float* bih  = (const float*)d_in[3];
  const float* bhh  = (const float*)d_in[4];
  const float* Wout = (const float*)d_in[5];
  const float* bout = (const float*)d_in[6];

  char* ws = (char*)d_ws;
  size_t off = 0;
  auto alloc = [&](size_t bytes) {
    void* p = ws + off;
    off = (off + bytes + 255) & ~(size_t)255;
    return p;
  };
  bf16_t* srcbf = (bf16_t*)alloc((size_t)S_SZ * B_SZ * DP * 2);   // 27.5 MB
  bf16_t* Wcat  = (bf16_t*)alloc((size_t)NG * KENC * 2);          // 10.2 MB
  bf16_t* Wdec  = (bf16_t*)alloc((size_t)NG * H_SZ * 2);          //  8.4 MB
  bf16_t* WoutB = (bf16_t*)alloc((size_t)256 * H_SZ * 2);
  bf16_t* WoutT = (bf16_t*)alloc((size_t)H_SZ * DP * 2);
  float*  biasE = (float*)alloc((size_t)NG * 4);
  float*  biasD = (float*)alloc((size_t)NG * 4);
  float*  cbuf  = (float*)alloc((size_t)B_SZ * H_SZ * 4);         //  2 MB
  bf16_t* hP0   = (bf16_t*)alloc((size_t)B_SZ * H_SZ * 2);
  bf16_t* hP1   = (bf16_t*)alloc((size_t)B_SZ * H_SZ * 2);
  bf16_t* Hs    = (bf16_t*)alloc((size_t)TMAX * B_SZ * H_SZ * 2); // 25.2 MB

  hipMemsetAsync(cbuf, 0, (size_t)B_SZ * H_SZ * 4, stream);
  hipMemsetAsync(hP0, 0, (size_t)B_SZ * H_SZ * 2, stream);

  k_convert_src<<<(S_SZ * B_SZ * DP + 255) / 256, 256, 0, stream>>>(src, srcbf);
  k_build_wcat<<<(NG * KENC + 255) / 256, 256, 0, stream>>>(Wih, Whh, Wcat);
  k_build_wout<<<1024, 256, 0, stream>>>(Wout, WoutB, WoutT);
  k_build_bias<<<(NG + 255) / 256, 256, 0, stream>>>(bih, bhh, Wih, bout, biasE, biasD);

  // W_dec = W_hh(reordered) + W_ih(reordered) @ W_out   (M=4096, N=1024, K=224)
  gemm_step<2><<<dim3(H_SZ / BN, NG / BM), 256, 0, stream>>>(
      Wcat, KENC, DP / BK, nullptr, 0, 0, WoutT, DP,
      nullptr, nullptr, nullptr, Whh, Wdec, nullptr);

  // 120 encoder steps + decoder step 0 (x = src_t[119]) + 23 folded decoder steps
  const bf16_t* hprev = hP0;
  for (int s = 0; s < 144; ++s) {
    bf16_t* hnext;
    if (s < 120) hnext = (hprev == hP0) ? hP1 : hP0;
    else         hnext = Hs + (size_t)(s - 120) * B_SZ * H_SZ;
    if (s <= 120) {
      int xi = (s <= 119) ? s : 119;
      gemm_step<1><<<dim3(NG / BN, B_SZ / BM), 256, 0, stream>>>(
          srcbf + (size_t)xi * B_SZ * DP, DP, DP / BK,
          hprev, H_SZ, H_SZ / BK,
          Wcat, KENC, biasE, cbuf, hnext,
          nullptr, nullptr, nullptr);
    } else {
      gemm_step<1><<<dim3(NG / BN, B_SZ / BM), 256, 0, stream>>>(
          nullptr, 0, 0, hprev, H_SZ, H_SZ / BK,
          Wdec, H_SZ, biasD, cbuf, hnext,
          nullptr, nullptr, nullptr);
    }
    hprev = hnext;
  }

  // Final projection: Y(12288 x 216) = Hs(12288 x 1024) @ W_out^T + b_out
  gemm_step<3><<<dim3(2, (TMAX * B_SZ) / BM), 256, 0, stream>>>(
      nullptr, 0, 0, Hs, H_SZ, H_SZ / BK, WoutB, H_SZ,
      bout, nullptr, nullptr, nullptr, nullptr, (float*)d_out);
}

// Round 2
// 2523.228 us; speedup vs baseline: 1.4156x; 1.4156x over previous
//
#include <hip/hip_runtime.h>
#include <cstdint>
#include <cstddef>

// Problem constants
#define B_SZ 512
#define S_SZ 120
#define D_SZ 216
#define H_SZ 1024
#define NG   4096     // 4*H
#define DP   256      // D padded to multiple of BK
#define KENC 1280     // DP + H
#define TMAX 24

// GEMM tile config
#define BM 64
#define BN 128
#define BK 64

using bf16_t = __bf16;
using bf16x8 = __attribute__((ext_vector_type(8))) __bf16;
using f32x4  = __attribute__((ext_vector_type(4))) float;

__device__ __forceinline__ void gload16(const void* g, void* l) {
  __builtin_amdgcn_global_load_lds(
      (const __attribute__((address_space(1))) void*)g,
      (__attribute__((address_space(3))) void*)l, 16, 0, 0);
}

__device__ __forceinline__ float fsigmoid(float x) {
  x = fminf(fmaxf(x, -30.f), 30.f);
  return 1.f / (1.f + __expf(-x));
}
__device__ __forceinline__ float ftanh(float x) {
  x = fminf(fmaxf(x, -15.f), 15.f);
  float e = __expf(2.f * x);
  return (e - 1.f) / (e + 1.f);
}

// LDS: two staging buffers (A 64x64 bf16 = 8KB, B 128x64 bf16 = 16KB each),
// gate restage union. Tiles stored [row][64] with XOR chunk swizzle applied
// on the GLOBAL fetch side: LDS slot (r, c) holds global 8-elem chunk c^(r&7).
struct __align__(16) Smem {
  union {
    bf16_t stage[2][(BM + BN) * BK];  // 49152 B
    float gate[BM * 129];             // 33024 B
  };
};

// C[m][n] = sum_k A[m][k] * W[n][k]  (K innermost; W is "B^T")
// A phases: (A1,sA1,n1 iters of BK) then (A2,sA2,n2 iters); W k advances 0..(n1+n2)*BK.
// EPI=1: LSTM cell epilogue (bias, cbuf fp32 in/out, hout bf16); N gate-interleaved.
// EPI=2: outb[m][n] = bf16(acc + addm[orig(m)][n])   (W_dec build)
// EPI=3: outf[(b*24+t)*216+n] = acc + bias[n], m = t*512+b, guard n<216
template <int EPI>
__global__ __launch_bounds__(256, 1) void gemm_step(
    const bf16_t* __restrict__ A1, int sA1, int n1,
    const bf16_t* __restrict__ A2, int sA2, int n2,
    const bf16_t* __restrict__ W, int sW,
    const float* __restrict__ bias,
    float* __restrict__ cbuf, bf16_t* __restrict__ hout,
    const float* __restrict__ addm, bf16_t* __restrict__ outb,
    float* __restrict__ outf)
{
  __shared__ Smem sm;
  const int t    = threadIdx.x;
  const int m0   = blockIdx.y * BM;
  const int n0   = blockIdx.x * BN;
  const int lane = t & 63;
  const int wv   = t >> 6;
  const int wm   = wv >> 1, wn = wv & 1;   // 2x2 wave grid, wave tile 32x64
  const int fr   = lane & 15;
  const int fq   = lane >> 4;

  f32x4 acc[2][4] = {};

  // ---- staging setup ----
  const int r0   = t >> 3;                       // 0..31 tile row (per load group)
  const int gcol = (((t & 7) ^ (r0 & 7)) * 8);   // swizzled global chunk (elems)
  char* ldsbase  = (char*)&sm.stage[0][0];
  const int wofs = wv * 1024;                    // wave-uniform LDS chunk

  const bf16_t* pA1 = A1 ? A1 : A2;
  const bf16_t* pA2 = A2 ? A2 : A1;
  const bf16_t* a1p0 = pA1 + (size_t)(m0 + r0) * sA1 + gcol;
  const bf16_t* a1p1 = pA1 + (size_t)(m0 + r0 + 32) * sA1 + gcol;
  const bf16_t* a2p0 = pA2 + (size_t)(m0 + r0) * sA2 + gcol;
  const bf16_t* a2p1 = pA2 + (size_t)(m0 + r0 + 32) * sA2 + gcol;
  const bf16_t* wp0  = W + (size_t)(n0 + r0) * sW + gcol;
  const bf16_t* wp1  = W + (size_t)(n0 + r0 + 32) * sW + gcol;
  const bf16_t* wp2  = W + (size_t)(n0 + r0 + 64) * sW + gcol;
  const bf16_t* wp3  = W + (size_t)(n0 + r0 + 96) * sW + gcol;

  const int nTot = n1 + n2;

  auto stage = [&](int j, int bf) {
    char* Ab = ldsbase + bf * 24576 + wofs;
    char* Bb = ldsbase + bf * 24576 + 8192 + wofs;
    const int k = j * BK;
    const bf16_t *a0, *a1;
    if (j < n1) { a0 = a1p0 + k; a1 = a1p1 + k; }
    else { const int k2 = k - n1 * BK; a0 = a2p0 + k2; a1 = a2p1 + k2; }
    gload16(a0, Ab);
    gload16(a1, Ab + 4096);
    gload16(wp0 + k, Bb);
    gload16(wp1 + k, Bb + 4096);
    gload16(wp2 + k, Bb + 8192);
    gload16(wp3 + k, Bb + 12288);
  };

  // ---- fragment read offsets (swizzle-aware, conflict-free) ----
  const int swz  = fr & 7;
  const int co0  = ((fq) ^ swz) * 16;        // kk=0 chunk byte offset
  const int co1  = ((4 + fq) ^ swz) * 16;    // kk=1
  const int arow0 = (wm * 32 + fr) * 128;
  const int arow1 = (wm * 32 + 16 + fr) * 128;
  const int brow  = (wn * 64 + fr) * 128;

  auto compute = [&](int bf) {
    const char* Ab = ldsbase + bf * 24576;
    const char* Bb = Ab + 8192;
#pragma unroll
    for (int kk = 0; kk < 2; ++kk) {
      const int co = kk ? co1 : co0;
      bf16x8 av0 = *(const bf16x8*)(Ab + arow0 + co);
      bf16x8 av1 = *(const bf16x8*)(Ab + arow1 + co);
      bf16x8 bv[4];
#pragma unroll
      for (int j = 0; j < 4; ++j)
        bv[j] = *(const bf16x8*)(Bb + brow + j * 2048 + co);
#pragma unroll
      for (int j = 0; j < 4; ++j) {
        acc[0][j] = __builtin_amdgcn_mfma_f32_16x16x32_bf16(av0, bv[j], acc[0][j], 0, 0, 0);
        acc[1][j] = __builtin_amdgcn_mfma_f32_16x16x32_bf16(av1, bv[j], acc[1][j], 0, 0, 0);
      }
    }
  };

  // ---- dual-buffered pipelined K-loop: one barrier per iter; the vmcnt
  // drain at the barrier lands AFTER this iter's compute, hiding latency ----
  stage(0, 0);
  __syncthreads();
  for (int it = 0; it < nTot; ++it) {
    if (it + 1 < nTot) stage(it + 1, (it + 1) & 1);
    compute(it & 1);
    __syncthreads();
  }

  if (EPI == 1) {
    // Restage gates (fp32, +bias) to LDS, then apply LSTM cell.
    // N layout is gate-interleaved: n = 4*unit + gate (i,f,g,o)
#pragma unroll
    for (int i = 0; i < 2; ++i)
#pragma unroll
      for (int j = 0; j < 4; ++j)
#pragma unroll
        for (int v = 0; v < 4; ++v) {
          int row = wm * 32 + i * 16 + fq * 4 + v;
          int col = wn * 64 + j * 16 + fr;
          sm.gate[row * 129 + col] = acc[i][j][v] + bias[n0 + col];
        }
    __syncthreads();
    const int u0 = n0 >> 2;
#pragma unroll
    for (int itc = 0; itc < 8; ++itc) {
      int ci = itc * 256 + t;
      int brw = ci >> 5;   // 0..63 local batch row
      int ju  = ci & 31;   // 0..31 local unit
      const float* gp = &sm.gate[brw * 129 + ju * 4];
      float iv = fsigmoid(gp[0]);
      float fv = fsigmoid(gp[1]);
      float gv = ftanh(gp[2]);
      float ov = fsigmoid(gp[3]);
      size_t cix = (size_t)(m0 + brw) * H_SZ + (u0 + ju);
      float cn = fv * cbuf[cix] + iv * gv;
      cbuf[cix] = cn;
      hout[cix] = (bf16_t)(ov * ftanh(cn));
    }
  }

  if (EPI == 2) {
#pragma unroll
    for (int i = 0; i < 2; ++i)
#pragma unroll
      for (int j = 0; j < 4; ++j)
#pragma unroll
        for (int v = 0; v < 4; ++v) {
          int gr = m0 + wm * 32 + i * 16 + fq * 4 + v;
          int gc = n0 + wn * 64 + j * 16 + fr;
          int orig = (gr & 3) * H_SZ + (gr >> 2);
          float val = acc[i][j][v] + addm[(size_t)orig * H_SZ + gc];
          outb[(size_t)gr * H_SZ + gc] = (bf16_t)val;
        }
  }

  if (EPI == 3) {
#pragma unroll
    for (int i = 0; i < 2; ++i)
#pragma unroll
      for (int j = 0; j < 4; ++j)
#pragma unroll
        for (int v = 0; v < 4; ++v) {
          int m = m0 + wm * 32 + i * 16 + fq * 4 + v;
          int n = n0 + wn * 64 + j * 16 + fr;
          if (n < D_SZ) {
            int ts = m >> 9;     // /512
            int bb = m & 511;
            outf[((size_t)bb * TMAX + ts) * D_SZ + n] = acc[i][j][v] + bias[n];
          }
        }
  }
}

// src (B,S,D) fp32 -> srcbf (S,B,DP) bf16, zero-padded d>=216
__global__ void k_convert_src(const float* __restrict__ src, bf16_t* __restrict__ dst) {
  int idx = blockIdx.x * 256 + threadIdx.x;
  int total = S_SZ * B_SZ * DP;
  if (idx >= total) return;
  int d = idx % DP;
  int r = idx / DP;
  int b = r % B_SZ;
  int tt = r / B_SZ;
  float v = (d < D_SZ) ? src[((size_t)b * S_SZ + tt) * D_SZ + d] : 0.f;
  dst[idx] = (bf16_t)v;
}

// W_cat (NG x KENC) bf16, rows gate-interleaved: row r <- orig (r&3)*H + (r>>2)
// cols [0,216)=W_ih, [216,256)=0, [256,1280)=W_hh
__global__ void k_build_wcat(const float* __restrict__ Wih, const float* __restrict__ Whh,
                             bf16_t* __restrict__ Wcat) {
  int idx = blockIdx.x * 256 + threadIdx.x;
  if (idx >= NG * KENC) return;
  int k = idx % KENC;
  int r = idx / KENC;
  int o = (r & 3) * H_SZ + (r >> 2);
  float v;
  if (k < D_SZ)      v = Wih[(size_t)o * D_SZ + k];
  else if (k < DP)   v = 0.f;
  else               v = Whh[(size_t)o * H_SZ + (k - DP)];
  Wcat[idx] = (bf16_t)v;
}

// WoutB: (256 x H) bf16, row d (zero-pad d>=216), col h  -- B-operand for final proj
// WoutT: (H x DP) bf16, row h, col d (zero-pad)          -- B-operand for W_dec build
__global__ void k_build_wout(const float* __restrict__ Wout, bf16_t* __restrict__ WoutB,
                             bf16_t* __restrict__ WoutT) {
  int idx = blockIdx.x * 256 + threadIdx.x;
  if (idx < 256 * H_SZ) {
    int h = idx % H_SZ, d = idx / H_SZ;
    WoutB[idx] = (bf16_t)((d < D_SZ) ? Wout[(size_t)d * H_SZ + h] : 0.f);
  }
  if (idx < H_SZ * DP) {
    int d = idx % DP, h = idx / DP;
    WoutT[idx] = (bf16_t)((d < D_SZ) ? Wout[(size_t)d * H_SZ + h] : 0.f);
  }
}

// bias_enc[r] = b_ih[o]+b_hh[o];  bias_dec[r] = bias_enc[r] + W_ih[o,:] . b_out
__global__ void k_build_bias(const float* __restrict__ bih, const float* __restrict__ bhh,
                             const float* __restrict__ Wih, const float* __restrict__ bout,
                             float* __restrict__ biasE, float* __restrict__ biasD) {
  int r = blockIdx.x * 256 + threadIdx.x;
  if (r >= NG) return;
  int o = (r & 3) * H_SZ + (r >> 2);
  float be = bih[o] + bhh[o];
  biasE[r] = be;
  float s = 0.f;
  const float* wr = Wih + (size_t)o * D_SZ;
  for (int d = 0; d < D_SZ; ++d) s += wr[d] * bout[d];
  biasD[r] = be + s;
}

extern "C" void kernel_launch(void* const* d_in, const int* in_sizes, int n_in,
                              void* d_out, int out_size, void* d_ws, size_t ws_size,
                              hipStream_t stream) {
  const float* src  = (const float*)d_in[0];
  const float* Wih  = (const float*)d_in[1];
  const float* Whh  = (const float*)d_in[2];
  const float* bih  = (const float*)d_in[3];
  const float* bhh  = (const float*)d_in[4];
  const float* Wout = (const float*)d_in[5];
  const float* bout = (const float*)d_in[6];

  char* ws = (char*)d_ws;
  size_t off = 0;
  auto alloc = [&](size_t bytes) {
    void* p = ws + off;
    off = (off + bytes + 255) & ~(size_t)255;
    return p;
  };
  bf16_t* srcbf = (bf16_t*)alloc((size_t)S_SZ * B_SZ * DP * 2);   // 31.5 MB
  bf16_t* Wcat  = (bf16_t*)alloc((size_t)NG * KENC * 2);          // 10.5 MB
  bf16_t* Wdec  = (bf16_t*)alloc((size_t)NG * H_SZ * 2);          //  8.4 MB
  bf16_t* WoutB = (bf16_t*)alloc((size_t)256 * H_SZ * 2);
  bf16_t* WoutT = (bf16_t*)alloc((size_t)H_SZ * DP * 2);
  float*  biasE = (float*)alloc((size_t)NG * 4);
  float*  biasD = (float*)alloc((size_t)NG * 4);
  float*  cbuf  = (float*)alloc((size_t)B_SZ * H_SZ * 4);         //  2 MB
  bf16_t* hP0   = (bf16_t*)alloc((size_t)B_SZ * H_SZ * 2);
  bf16_t* hP1   = (bf16_t*)alloc((size_t)B_SZ * H_SZ * 2);
  bf16_t* Hs    = (bf16_t*)alloc((size_t)TMAX * B_SZ * H_SZ * 2); // 25.2 MB

  hipMemsetAsync(cbuf, 0, (size_t)B_SZ * H_SZ * 4, stream);
  hipMemsetAsync(hP0, 0, (size_t)B_SZ * H_SZ * 2, stream);

  k_convert_src<<<(S_SZ * B_SZ * DP + 255) / 256, 256, 0, stream>>>(src, srcbf);
  k_build_wcat<<<(NG * KENC + 255) / 256, 256, 0, stream>>>(Wih, Whh, Wcat);
  k_build_wout<<<1024, 256, 0, stream>>>(Wout, WoutB, WoutT);
  k_build_bias<<<(NG + 255) / 256, 256, 0, stream>>>(bih, bhh, Wih, bout, biasE, biasD);

  // W_dec = W_hh(reordered) + W_ih(reordered) @ W_out   (M=4096, N=1024, K=256)
  gemm_step<2><<<dim3(H_SZ / BN, NG / BM), 256, 0, stream>>>(
      Wcat, KENC, DP / BK, nullptr, 0, 0, WoutT, DP,
      nullptr, nullptr, nullptr, Whh, Wdec, nullptr);

  // 120 encoder steps + decoder step 0 (x = src_t[119]) + 23 folded decoder steps
  const bf16_t* hprev = hP0;
  for (int s = 0; s < 144; ++s) {
    bf16_t* hnext;
    if (s < 120) hnext = (hprev == hP0) ? hP1 : hP0;
    else         hnext = Hs + (size_t)(s - 120) * B_SZ * H_SZ;
    if (s <= 120) {
      int xi = (s <= 119) ? s : 119;
      gemm_step<1><<<dim3(NG / BN, B_SZ / BM), 256, 0, stream>>>(
          srcbf + (size_t)xi * B_SZ * DP, DP, DP / BK,
          hprev, H_SZ, H_SZ / BK,
          Wcat, KENC, biasE, cbuf, hnext,
          nullptr, nullptr, nullptr);
    } else {
      gemm_step<1><<<dim3(NG / BN, B_SZ / BM), 256, 0, stream>>>(
          nullptr, 0, 0, hprev, H_SZ, H_SZ / BK,
          Wdec, H_SZ, biasD, cbuf, hnext,
          nullptr, nullptr, nullptr);
    }
    hprev = hnext;
  }

  // Final projection: Y(12288 x 216) = Hs(12288 x 1024) @ W_out^T + b_out
  gemm_step<3><<<dim3(2, (TMAX * B_SZ) / BM), 256, 0, stream>>>(
      nullptr, 0, 0, Hs, H_SZ, H_SZ / BK, WoutB, H_SZ,
      bout, nullptr, nullptr, nullptr, nullptr, (float*)d_out);
}

// Round 3
// 2017.860 us; speedup vs baseline: 1.7702x; 1.2504x over previous
//
#include <hip/hip_runtime.h>
#include <cstdint>
#include <cstddef>

// Problem constants
#define B_SZ 512
#define S_SZ 120
#define D_SZ 216
#define H_SZ 1024
#define NG   4096     // 4*H
#define DP   256      // D padded to multiple of BK
#define KENC 1280     // DP + H
#define TMAX 24

// GEMM tile config
#define BM 64
#define BN 128
#define BK 64

using bf16_t = __bf16;
using bf16x8 = __attribute__((ext_vector_type(8))) __bf16;
using f32x4  = __attribute__((ext_vector_type(4))) float;

__device__ __forceinline__ void gload16(const void* g, void* l) {
  __builtin_amdgcn_global_load_lds(
      (const __attribute__((address_space(1))) void*)g,
      (__attribute__((address_space(3))) void*)l, 16, 0, 0);
}

__device__ __forceinline__ float fsigmoid(float x) {
  x = fminf(fmaxf(x, -30.f), 30.f);
  return 1.f / (1.f + __expf(-x));
}
__device__ __forceinline__ float ftanh(float x) {
  x = fminf(fmaxf(x, -15.f), 15.f);
  float e = __expf(2.f * x);
  return (e - 1.f) / (e + 1.f);
}

// LDS: THREE staging buffers (A 64x64 bf16 = 8KB + B 128x64 bf16 = 16KB each),
// gate restage union. Tiles stored [row][64] with XOR chunk swizzle applied on
// the GLOBAL fetch side: LDS slot (r, c) holds global 8-elem chunk c^(r&7).
#define BUFB 24576
struct __align__(16) Smem {
  union {
    bf16_t stage[3][(BM + BN) * BK];  // 73728 B
    float gate[BM * 129];             // 33024 B
  };
};

// C[m][n] = sum_k A[m][k] * W[n][k]  (K innermost; W is "B^T")
// A phases: (A1,sA1,n1 iters of BK) then (A2,sA2,n2 iters); W k advances 0..(n1+n2)*BK.
// EPI=1: LSTM cell epilogue (bias, cbuf fp32 in/out, hout bf16); N gate-interleaved.
// EPI=2: outb[m][n] = bf16(acc + addm[orig(m)][n])   (W_dec build)
// EPI=3: outf[(b*24+t)*216+n] = acc + bias[n], m = t*512+b, guard n<216
template <int EPI>
__global__ __launch_bounds__(256, 1) void gemm_step(
    const bf16_t* __restrict__ A1, int sA1, int n1,
    const bf16_t* __restrict__ A2, int sA2, int n2,
    const bf16_t* __restrict__ W, int sW,
    const float* __restrict__ bias,
    float* __restrict__ cbuf, bf16_t* __restrict__ hout,
    const float* __restrict__ addm, bf16_t* __restrict__ outb,
    float* __restrict__ outf)
{
  __shared__ Smem sm;
  const int t    = threadIdx.x;
  const int m0   = blockIdx.y * BM;
  const int n0   = blockIdx.x * BN;
  const int lane = t & 63;
  const int wv   = t >> 6;
  const int wm   = wv >> 1, wn = wv & 1;   // 2x2 wave grid, wave tile 32x64
  const int fr   = lane & 15;
  const int fq   = lane >> 4;

  f32x4 acc[2][4] = {};

  // Prefetch epilogue bias into registers (covered by the pipeline's vmcnt waits)
  float bias4[4];
  if (EPI == 1 || EPI == 3) {
#pragma unroll
    for (int j = 0; j < 4; ++j) {
      int col = n0 + wn * 64 + j * 16 + fr;
      bias4[j] = (EPI == 3 && col >= D_SZ) ? 0.f : bias[col];
    }
  }

  // ---- staging setup ----
  const int r0   = t >> 3;                       // 0..31 tile row (per load group)
  const int gcol = (((t & 7) ^ (r0 & 7)) * 8);   // swizzled global chunk (elems)
  char* ldsbase  = (char*)&sm.stage[0][0];
  const int wofs = wv * 1024;                    // wave-uniform LDS chunk

  const bf16_t* pA1 = A1 ? A1 : A2;
  const bf16_t* pA2 = A2 ? A2 : A1;
  const bf16_t* a1p0 = pA1 + (size_t)(m0 + r0) * sA1 + gcol;
  const bf16_t* a1p1 = pA1 + (size_t)(m0 + r0 + 32) * sA1 + gcol;
  const bf16_t* a2p0 = pA2 + (size_t)(m0 + r0) * sA2 + gcol;
  const bf16_t* a2p1 = pA2 + (size_t)(m0 + r0 + 32) * sA2 + gcol;
  const bf16_t* wp0  = W + (size_t)(n0 + r0) * sW + gcol;
  const bf16_t* wp1  = W + (size_t)(n0 + r0 + 32) * sW + gcol;
  const bf16_t* wp2  = W + (size_t)(n0 + r0 + 64) * sW + gcol;
  const bf16_t* wp3  = W + (size_t)(n0 + r0 + 96) * sW + gcol;

  const int nTot = n1 + n2;

  auto stage = [&](int j, int bf) {
    char* Ab = ldsbase + bf * BUFB + wofs;
    char* Bb = ldsbase + bf * BUFB + 8192 + wofs;
    const int k = j * BK;
    const bf16_t *a0, *a1;
    if (j < n1) { a0 = a1p0 + k; a1 = a1p1 + k; }
    else { const int k2 = k - n1 * BK; a0 = a2p0 + k2; a1 = a2p1 + k2; }
    gload16(a0, Ab);
    gload16(a1, Ab + 4096);
    gload16(wp0 + k, Bb);
    gload16(wp1 + k, Bb + 4096);
    gload16(wp2 + k, Bb + 8192);
    gload16(wp3 + k, Bb + 12288);
  };

  // ---- fragment read offsets (swizzle-aware, conflict-free) ----
  const int swz  = fr & 7;
  const int co0  = ((fq) ^ swz) * 16;        // kk=0 chunk byte offset
  const int co1  = ((4 + fq) ^ swz) * 16;    // kk=1
  const int arow0 = (wm * 32 + fr) * 128;
  const int arow1 = (wm * 32 + 16 + fr) * 128;
  const int brow  = (wn * 64 + fr) * 128;

  auto compute = [&](int bf) {
    const char* Ab = ldsbase + bf * BUFB;
    const char* Bb = Ab + 8192;
#pragma unroll
    for (int kk = 0; kk < 2; ++kk) {
      const int co = kk ? co1 : co0;
      bf16x8 av0 = *(const bf16x8*)(Ab + arow0 + co);
      bf16x8 av1 = *(const bf16x8*)(Ab + arow1 + co);
      bf16x8 bv[4];
#pragma unroll
      for (int j = 0; j < 4; ++j)
        bv[j] = *(const bf16x8*)(Bb + brow + j * 2048 + co);
#pragma unroll
      for (int j = 0; j < 4; ++j) {
        acc[0][j] = __builtin_amdgcn_mfma_f32_16x16x32_bf16(av0, bv[j], acc[0][j], 0, 0, 0);
        acc[1][j] = __builtin_amdgcn_mfma_f32_16x16x32_bf16(av1, bv[j], acc[1][j], 0, 0, 0);
      }
    }
  };

  // ---- 3-buffer pipelined K-loop, prefetch depth 2, raw barriers, explicit
  // vmcnt(6): buf(it)'s 6 loads are 2 iters old when waited -> wait is
  // bandwidth-limited, never latency-limited. No vmcnt(0) drain in the loop.
  stage(0, 0);
  if (nTot > 1) stage(1, 1);
  int cb = 0, sb = 2;  // compute buffer, stage buffer
  for (int it = 0; it < nTot; ++it) {
    if (it == nTot - 1) {
      asm volatile("s_waitcnt vmcnt(0)" ::: "memory");
    } else {
      asm volatile("s_waitcnt vmcnt(6)" ::: "memory");
    }
    __builtin_amdgcn_s_barrier();  // fences compute(it-1) vs stage(it+2); no vm drain
    if (it + 2 < nTot) stage(it + 2, sb);
    sb = (sb == 2) ? 0 : sb + 1;
    compute(cb);
    cb = (cb == 2) ? 0 : cb + 1;
  }
  __syncthreads();  // before gate-restage union reuse

  if (EPI == 1) {
    // Restage gates (fp32, +bias) to LDS, then apply LSTM cell.
    // N layout is gate-interleaved: n = 4*unit + gate (i,f,g,o)
#pragma unroll
    for (int i = 0; i < 2; ++i)
#pragma unroll
      for (int j = 0; j < 4; ++j)
#pragma unroll
        for (int v = 0; v < 4; ++v) {
          int row = wm * 32 + i * 16 + fq * 4 + v;
          int col = wn * 64 + j * 16 + fr;
          sm.gate[row * 129 + col] = acc[i][j][v] + bias4[j];
        }
    __syncthreads();
    const int u0 = n0 >> 2;
#pragma unroll
    for (int itc = 0; itc < 8; ++itc) {
      int ci = itc * 256 + t;
      int brw = ci >> 5;   // 0..63 local batch row
      int ju  = ci & 31;   // 0..31 local unit
      const float* gp = &sm.gate[brw * 129 + ju * 4];
      float iv = fsigmoid(gp[0]);
      float fv = fsigmoid(gp[1]);
      float gv = ftanh(gp[2]);
      float ov = fsigmoid(gp[3]);
      size_t cix = (size_t)(m0 + brw) * H_SZ + (u0 + ju);
      float cn = fv * cbuf[cix] + iv * gv;
      cbuf[cix] = cn;
      hout[cix] = (bf16_t)(ov * ftanh(cn));
    }
  }

  if (EPI == 2) {
#pragma unroll
    for (int i = 0; i < 2; ++i)
#pragma unroll
      for (int j = 0; j < 4; ++j)
#pragma unroll
        for (int v = 0; v < 4; ++v) {
          int gr = m0 + wm * 32 + i * 16 + fq * 4 + v;
          int gc = n0 + wn * 64 + j * 16 + fr;
          int orig = (gr & 3) * H_SZ + (gr >> 2);
          float val = acc[i][j][v] + addm[(size_t)orig * H_SZ + gc];
          outb[(size_t)gr * H_SZ + gc] = (bf16_t)val;
        }
  }

  if (EPI == 3) {
#pragma unroll
    for (int i = 0; i < 2; ++i)
#pragma unroll
      for (int j = 0; j < 4; ++j)
#pragma unroll
        for (int v = 0; v < 4; ++v) {
          int m = m0 + wm * 32 + i * 16 + fq * 4 + v;
          int n = n0 + wn * 64 + j * 16 + fr;
          if (n < D_SZ) {
            int ts = m >> 9;     // /512
            int bb = m & 511;
            outf[((size_t)bb * TMAX + ts) * D_SZ + n] = acc[i][j][v] + bias4[j];
          }
        }
  }
}

// src (B,S,D) fp32 -> srcbf (S,B,DP) bf16, zero-padded d>=216
__global__ void k_convert_src(const float* __restrict__ src, bf16_t* __restrict__ dst) {
  int idx = blockIdx.x * 256 + threadIdx.x;
  int total = S_SZ * B_SZ * DP;
  if (idx >= total) return;
  int d = idx % DP;
  int r = idx / DP;
  int b = r % B_SZ;
  int tt = r / B_SZ;
  float v = (d < D_SZ) ? src[((size_t)b * S_SZ + tt) * D_SZ + d] : 0.f;
  dst[idx] = (bf16_t)v;
}

// W_cat (NG x KENC) bf16, rows gate-interleaved: row r <- orig (r&3)*H + (r>>2)
// cols [0,216)=W_ih, [216,256)=0, [256,1280)=W_hh
__global__ void k_build_wcat(const float* __restrict__ Wih, const float* __restrict__ Whh,
                             bf16_t* __restrict__ Wcat) {
  int idx = blockIdx.x * 256 + threadIdx.x;
  if (idx >= NG * KENC) return;
  int k = idx % KENC;
  int r = idx / KENC;
  int o = (r & 3) * H_SZ + (r >> 2);
  float v;
  if (k < D_SZ)      v = Wih[(size_t)o * D_SZ + k];
  else if (k < DP)   v = 0.f;
  else               v = Whh[(size_t)o * H_SZ + (k - DP)];
  Wcat[idx] = (bf16_t)v;
}

// WoutB: (256 x H) bf16, row d (zero-pad d>=216), col h  -- B-operand for final proj
// WoutT: (H x DP) bf16, row h, col d (zero-pad)          -- B-operand for W_dec build
__global__ void k_build_wout(const float* __restrict__ Wout, bf16_t* __restrict__ WoutB,
                             bf16_t* __restrict__ WoutT) {
  int idx = blockIdx.x * 256 + threadIdx.x;
  if (idx < 256 * H_SZ) {
    int h = idx % H_SZ, d = idx / H_SZ;
    WoutB[idx] = (bf16_t)((d < D_SZ) ? Wout[(size_t)d * H_SZ + h] : 0.f);
  }
  if (idx < H_SZ * DP) {
    int d = idx % DP, h = idx / DP;
    WoutT[idx] = (bf16_t)((d < D_SZ) ? Wout[(size_t)d * H_SZ + h] : 0.f);
  }
}

// bias_enc[r] = b_ih[o]+b_hh[o];  bias_dec[r] = bias_enc[r] + W_ih[o,:] . b_out
__global__ void k_build_bias(const float* __restrict__ bih, const float* __restrict__ bhh,
                             const float* __restrict__ Wih, const float* __restrict__ bout,
                             float* __restrict__ biasE, float* __restrict__ biasD) {
  int r = blockIdx.x * 256 + threadIdx.x;
  if (r >= NG) return;
  int o = (r & 3) * H_SZ + (r >> 2);
  float be = bih[o] + bhh[o];
  biasE[r] = be;
  float s = 0.f;
  const float* wr = Wih + (size_t)o * D_SZ;
  for (int d = 0; d < D_SZ; ++d) s += wr[d] * bout[d];
  biasD[r] = be + s;
}

extern "C" void kernel_launch(void* const* d_in, const int* in_sizes, int n_in,
                              void* d_out, int out_size, void* d_ws, size_t ws_size,
                              hipStream_t stream) {
  const float* src  = (const float*)d_in[0];
  const float* Wih  = (const float*)d_in[1];
  const float* Whh  = (const float*)d_in[2];
  const float* bih  = (const float*)d_in[3];
  const float* bhh  = (const float*)d_in[4];
  const float* Wout = (const float*)d_in[5];
  const float* bout = (const float*)d_in[6];

  char* ws = (char*)d_ws;
  size_t off = 0;
  auto alloc = [&](size_t bytes) {
    void* p = ws + off;
    off = (off + bytes + 255) & ~(size_t)255;
    return p;
  };
  bf16_t* srcbf = (bf16_t*)alloc((size_t)S_SZ * B_SZ * DP * 2);   // 31.5 MB
  bf16_t* Wcat  = (bf16_t*)alloc((size_t)NG * KENC * 2);          // 10.5 MB
  bf16_t* Wdec  = (bf16_t*)alloc((size_t)NG * H_SZ * 2);          //  8.4 MB
  bf16_t* WoutB = (bf16_t*)alloc((size_t)256 * H_SZ * 2);
  bf16_t* WoutT = (bf16_t*)alloc((size_t)H_SZ * DP * 2);
  float*  biasE = (float*)alloc((size_t)NG * 4);
  float*  biasD = (float*)alloc((size_t)NG * 4);
  float*  cbuf  = (float*)alloc((size_t)B_SZ * H_SZ * 4);         //  2 MB
  bf16_t* hP0   = (bf16_t*)alloc((size_t)B_SZ * H_SZ * 2);
  bf16_t* hP1   = (bf16_t*)alloc((size_t)B_SZ * H_SZ * 2);
  bf16_t* Hs    = (bf16_t*)alloc((size_t)TMAX * B_SZ * H_SZ * 2); // 25.2 MB

  hipMemsetAsync(cbuf, 0, (size_t)B_SZ * H_SZ * 4, stream);
  hipMemsetAsync(hP0, 0, (size_t)B_SZ * H_SZ * 2, stream);

  k_convert_src<<<(S_SZ * B_SZ * DP + 255) / 256, 256, 0, stream>>>(src, srcbf);
  k_build_wcat<<<(NG * KENC + 255) / 256, 256, 0, stream>>>(Wih, Whh, Wcat);
  k_build_wout<<<1024, 256, 0, stream>>>(Wout, WoutB, WoutT);
  k_build_bias<<<(NG + 255) / 256, 256, 0, stream>>>(bih, bhh, Wih, bout, biasE, biasD);

  // W_dec = W_hh(reordered) + W_ih(reordered) @ W_out   (M=4096, N=1024, K=256)
  gemm_step<2><<<dim3(H_SZ / BN, NG / BM), 256, 0, stream>>>(
      Wcat, KENC, DP / BK, nullptr, 0, 0, WoutT, DP,
      nullptr, nullptr, nullptr, Whh, Wdec, nullptr);

  // 120 encoder steps + decoder step 0 (x = src_t[119]) + 23 folded decoder steps
  const bf16_t* hprev = hP0;
  for (int s = 0; s < 144; ++s) {
    bf16_t* hnext;
    if (s < 120) hnext = (hprev == hP0) ? hP1 : hP0;
    else         hnext = Hs + (size_t)(s - 120) * B_SZ * H_SZ;
    if (s <= 120) {
      int xi = (s <= 119) ? s : 119;
      gemm_step<1><<<dim3(NG / BN, B_SZ / BM), 256, 0, stream>>>(
          srcbf + (size_t)xi * B_SZ * DP, DP, DP / BK,
          hprev, H_SZ, H_SZ / BK,
          Wcat, KENC, biasE, cbuf, hnext,
          nullptr, nullptr, nullptr);
    } else {
      gemm_step<1><<<dim3(NG / BN, B_SZ / BM), 256, 0, stream>>>(
          nullptr, 0, 0, hprev, H_SZ, H_SZ / BK,
          Wdec, H_SZ, biasD, cbuf, hnext,
          nullptr, nullptr, nullptr);
    }
    hprev = hnext;
  }

  // Final projection: Y(12288 x 216) = Hs(12288 x 1024) @ W_out^T + b_out
  gemm_step<3><<<dim3(2, (TMAX * B_SZ) / BM), 256, 0, stream>>>(
      nullptr, 0, 0, Hs, H_SZ, H_SZ / BK, WoutB, H_SZ,
      bout, nullptr, nullptr, nullptr, nullptr, (float*)d_out);
}